// Round 5
// baseline (285.691 us; speedup 1.0000x reference)
//
#include <hip/hip_runtime.h>

#define NC 91
#define NB 32
#define HW (1024 * 1024)

#define THREADS 256
#define PPT 64                          // pixels per thread
#define PIX_PER_BLOCK (THREADS * PPT)   // 16384
#define WPT 23                          // ceil(91/4) words, odd stride -> full bank spread

// Round-5: per-thread private 8-bit-packed histograms with PLAIN ds_read/
// ds_write (no atomics - the histogram is private), restructured for deep
// DS ILP: 4 labels per batch = 4 reads -> one wait -> branchless same-word
// merge -> 4 writes. DS ops from one wave execute in order, so:
//  - within a batch, all reads see the pre-batch value; writes go in program
//    order and the LAST same-word write carries the merged total (exact).
//  - across batches, a later read sees the earlier write (in-order pipe).
// Max per-byte count = 2*PPT = 128 <= 255: no field carry.

__device__ __forceinline__ void batch4(int l0, int l1, int l2, int l3, int* hp) {
    const int w0 = l0 >> 2, w1 = l1 >> 2, w2 = l2 >> 2, w3 = l3 >> 2;
    const int o0 = 1 << ((l0 & 3) << 3);
    const int o1 = 1 << ((l1 & 3) << 3);
    const int o2 = 1 << ((l2 & 3) << 3);
    const int o3 = 1 << ((l3 & 3) << 3);
    // 4 independent reads (single wait, 4 in flight)
    const int v0 = hp[w0];
    const int v1 = hp[w1];
    const int v2 = hp[w2];
    const int v3 = hp[w3];
    // merge increments of earlier same-word labels (use ORIGINAL o's)
    const int i1 = o1 + ((w0 == w1) ? o0 : 0);
    const int i2 = o2 + ((w0 == w2) ? o0 : 0) + ((w1 == w2) ? o1 : 0);
    const int i3 = o3 + ((w0 == w3) ? o0 : 0) + ((w1 == w3) ? o1 : 0)
                      + ((w2 == w3) ? o2 : 0);
    // writes in program order: last same-word write wins with the full sum
    hp[w0] = v0 + o0;
    hp[w1] = v1 + i1;
    hp[w2] = v2 + i2;
    hp[w3] = v3 + i3;
}

__global__ __launch_bounds__(256, 6) void hist_kernel(const int* __restrict__ x,
                                                      const int* __restrict__ t,
                                                      int* __restrict__ g_hist,
                                                      int* __restrict__ g_inter) {
    __shared__ int s_hist[THREADS * WPT];   // 23,552 B packed private histograms
    __shared__ int s_inter[NC];             // block-wide intersection (rare hits)
    __shared__ int s_p[8][WPT * 4];         // stage-1 partials

    const int tid = threadIdx.x;
    int* hp = &s_hist[tid * WPT];
#pragma unroll
    for (int j = 0; j < WPT; ++j) hp[j] = 0;
    if (tid < NC) s_inter[tid] = 0;
    __syncthreads();

    const int b = blockIdx.y;
    const long base = (long)b * HW + (long)blockIdx.x * PIX_PER_BLOCK;
    const int4* __restrict__ x4 = (const int4*)(x + base);
    const int4* __restrict__ t4 = (const int4*)(t + base);

    const int n = PPT / 4;   // 16 iterations, 4 pixels each
    int4 xv0 = x4[tid],           tv0 = t4[tid];
    int4 xv1 = x4[THREADS + tid], tv1 = t4[THREADS + tid];

    for (int i = 0; i < n; ++i) {
        const int pf = (i + 2 < n) ? (i + 2) : (n - 1);   // clamped prefetch
        int4 xn = x4[pf * THREADS + tid];
        int4 tn = t4[pf * THREADS + tid];

        // pair each x with its own t so the x==t same-word case merges in-batch
        batch4(xv0.x, tv0.x, xv0.y, tv0.y, hp);
        batch4(xv0.z, tv0.z, xv0.w, tv0.w, hp);

        // intersection: ~1/91 of lanes active -> cheap masked atomic
        if (xv0.x == tv0.x) atomicAdd(&s_inter[xv0.x], 1);
        if (xv0.y == tv0.y) atomicAdd(&s_inter[xv0.y], 1);
        if (xv0.z == tv0.z) atomicAdd(&s_inter[xv0.z], 1);
        if (xv0.w == tv0.w) atomicAdd(&s_inter[xv0.w], 1);

        xv0 = xv1; tv0 = tv1;
        xv1 = xn;  tv1 = tn;
    }
    __syncthreads();

    // Stage 1: fold 256 private copies in 8 chunks of 32, unpacking 8-bit
    // fields into 32-bit partials (max 32*128 = 4096 per field).
    const int chunk = tid >> 5;
    const int w = tid & 31;
    if (w < WPT) {
        int f0 = 0, f1 = 0, f2 = 0, f3 = 0;
        const int kb = chunk * 32;
        for (int k = 0; k < 32; ++k) {
            unsigned v = (unsigned)s_hist[(kb + k) * WPT + w];
            f0 += (int)(v & 0xffu);
            f1 += (int)((v >> 8) & 0xffu);
            f2 += (int)((v >> 16) & 0xffu);
            f3 += (int)(v >> 24);
        }
        s_p[chunk][w * 4 + 0] = f0;
        s_p[chunk][w * 4 + 1] = f1;
        s_p[chunk][w * 4 + 2] = f2;
        s_p[chunk][w * 4 + 3] = f3;
    }
    __syncthreads();

    // Stage 2: combine 8 chunk partials, one global atomic per class.
    if (tid < NC) {
        int sum = 0;
#pragma unroll
        for (int ch = 0; ch < 8; ++ch) sum += s_p[ch][tid];
        if (sum) atomicAdd(&g_hist[b * NC + tid], sum);   // cnt_x + cnt_t
        const int in = s_inter[tid];
        if (in)  atomicAdd(&g_inter[b * NC + tid], in);
    }
}

__global__ __launch_bounds__(64) void finalize_kernel(const int* __restrict__ g_hist,
                                                      const int* __restrict__ g_inter,
                                                      const float* __restrict__ smooth,
                                                      float* __restrict__ out) {
    const int b = blockIdx.x;
    const int lane = threadIdx.x;  // 0..63
    const float s = smooth[0];
    float acc = 0.0f;
    for (int c = lane; c < NC; c += 64) {
        float in = (float)g_inter[b * NC + c];
        float ht = (float)g_hist[b * NC + c];   // cnt_x + cnt_t
        // union = cnt_x + cnt_t - inter
        acc += (in + s) / (ht - in + s);
    }
#pragma unroll
    for (int off = 32; off > 0; off >>= 1)
        acc += __shfl_down(acc, off, 64);
    if (lane == 0) out[b] = acc / (float)NC;
}

extern "C" void kernel_launch(void* const* d_in, const int* in_sizes, int n_in,
                              void* d_out, int out_size, void* d_ws, size_t ws_size,
                              hipStream_t stream) {
    const int* x = (const int*)d_in[0];
    const int* t = (const int*)d_in[1];
    const float* smooth = (const float*)d_in[2];
    float* out = (float*)d_out;

    int* g_hist = (int*)d_ws;
    int* g_inter = g_hist + NB * NC;

    hipMemsetAsync(d_ws, 0, 2 * NB * NC * sizeof(int), stream);

    dim3 grid(HW / PIX_PER_BLOCK, NB);  // 64 x 32 = 2048 blocks
    hist_kernel<<<grid, THREADS, 0, stream>>>(x, t, g_hist, g_inter);
    finalize_kernel<<<NB, 64, 0, stream>>>(g_hist, g_inter, smooth, out);
}

// Round 6
// 283.878 us; speedup vs baseline: 1.0064x; 1.0064x over previous
//
#include <hip/hip_runtime.h>

#define NC 91
#define NB 32
#define HW (1024 * 1024)

#define THREADS 256
#define PPT 64                          // pixels per thread
#define PIX_PER_BLOCK (THREADS * PPT)   // 16384
#define WPT 23                          // ceil(91/4) packed words per thread

// Round-6: COLUMN-MAJOR per-thread packed histograms.
// Word w of thread tid lives at s_hist[w*256 + tid]. Byte address =
// w*1024 + tid*4, and 1024 % 128 == 0, so bank = tid & 31 — a CONSTANT,
// independent of the label. Every ds_read/ds_write is an exact 2-way
// (2 lanes/bank) access, which is free (m136). This removes the random
// 5-way-max bank load that made scattered DS cost ~31 cyc/wave-instr
// (the invariant ~107 us wall of rounds 2-5).
// Histogram remains private per thread -> plain read+merge+write, no atomics.
// 8-bit fields, max per-byte count = 2*PPT = 128 <= 255: no carry.

__device__ __forceinline__ void batch4(int l0, int l1, int l2, int l3,
                                       int* __restrict__ col) {
    const int w0 = l0 >> 2, w1 = l1 >> 2, w2 = l2 >> 2, w3 = l3 >> 2;
    const int o0 = 1 << ((l0 & 3) << 3);
    const int o1 = 1 << ((l1 & 3) << 3);
    const int o2 = 1 << ((l2 & 3) << 3);
    const int o3 = 1 << ((l3 & 3) << 3);
    // 4 independent reads (one wait, 4 in flight), bank = tid&31 for all
    const int v0 = col[w0 << 8];
    const int v1 = col[w1 << 8];
    const int v2 = col[w2 << 8];
    const int v3 = col[w3 << 8];
    // merge increments of earlier same-word labels
    const int i1 = o1 + ((w0 == w1) ? o0 : 0);
    const int i2 = o2 + ((w0 == w2) ? o0 : 0) + ((w1 == w2) ? o1 : 0);
    const int i3 = o3 + ((w0 == w3) ? o0 : 0) + ((w1 == w3) ? o1 : 0)
                      + ((w2 == w3) ? o2 : 0);
    // writes in program order: last same-word write wins with the full sum
    col[w0 << 8] = v0 + o0;
    col[w1 << 8] = v1 + i1;
    col[w2 << 8] = v2 + i2;
    col[w3 << 8] = v3 + i3;
}

__global__ __launch_bounds__(256, 6) void hist_kernel(const int* __restrict__ x,
                                                      const int* __restrict__ t,
                                                      int* __restrict__ g_hist,
                                                      int* __restrict__ g_inter) {
    __shared__ int s_hist[WPT * THREADS];   // 23,552 B, column-major [w][tid]
    __shared__ int s_inter[NC];             // block-wide intersection (rare hits)
    __shared__ int s_p[8][WPT * 4];         // stage-1 partials

    const int tid = threadIdx.x;
    int* col = &s_hist[tid];
#pragma unroll
    for (int w = 0; w < WPT; ++w) col[w << 8] = 0;
    if (tid < NC) s_inter[tid] = 0;
    __syncthreads();

    const int b = blockIdx.y;
    const long base = (long)b * HW + (long)blockIdx.x * PIX_PER_BLOCK;
    const int4* __restrict__ x4 = (const int4*)(x + base);
    const int4* __restrict__ t4 = (const int4*)(t + base);

    const int n = PPT / 4;   // 16 iterations, 4 pixels each
    int4 xv0 = x4[tid],           tv0 = t4[tid];
    int4 xv1 = x4[THREADS + tid], tv1 = t4[THREADS + tid];

    for (int i = 0; i < n; ++i) {
        const int pf = (i + 2 < n) ? (i + 2) : (n - 1);   // clamped prefetch
        int4 xn = x4[pf * THREADS + tid];
        int4 tn = t4[pf * THREADS + tid];

        // pair each x with its own t so the x==t same-word case merges in-batch
        batch4(xv0.x, tv0.x, xv0.y, tv0.y, col);
        batch4(xv0.z, tv0.z, xv0.w, tv0.w, col);

        // intersection: ~1/91 of lanes active -> cheap masked atomic
        if (xv0.x == tv0.x) atomicAdd(&s_inter[xv0.x], 1);
        if (xv0.y == tv0.y) atomicAdd(&s_inter[xv0.y], 1);
        if (xv0.z == tv0.z) atomicAdd(&s_inter[xv0.z], 1);
        if (xv0.w == tv0.w) atomicAdd(&s_inter[xv0.w], 1);

        xv0 = xv1; tv0 = tv1;
        xv1 = xn;  tv1 = tn;
    }
    __syncthreads();

    // Stage 1: fold 256 columns in 8 chunks of 32, unpacking 8-bit fields.
    // Rotation (k+w)&31 keeps lane banks distinct: bank = (kb + k + w) & 31.
    const int chunk = tid >> 5;
    const int w = tid & 31;
    if (w < WPT) {
        int f0 = 0, f1 = 0, f2 = 0, f3 = 0;
        const int kb = chunk * 32;
        for (int k = 0; k < 32; ++k) {
            unsigned v = (unsigned)s_hist[(w << 8) + kb + ((k + w) & 31)];
            f0 += (int)(v & 0xffu);
            f1 += (int)((v >> 8) & 0xffu);
            f2 += (int)((v >> 16) & 0xffu);
            f3 += (int)(v >> 24);
        }
        s_p[chunk][w * 4 + 0] = f0;
        s_p[chunk][w * 4 + 1] = f1;
        s_p[chunk][w * 4 + 2] = f2;
        s_p[chunk][w * 4 + 3] = f3;
    }
    __syncthreads();

    // Stage 2: combine 8 chunk partials, one global atomic per class.
    if (tid < NC) {
        int sum = 0;
#pragma unroll
        for (int ch = 0; ch < 8; ++ch) sum += s_p[ch][tid];
        if (sum) atomicAdd(&g_hist[b * NC + tid], sum);   // cnt_x + cnt_t
        const int in = s_inter[tid];
        if (in)  atomicAdd(&g_inter[b * NC + tid], in);
    }
}

__global__ __launch_bounds__(64) void finalize_kernel(const int* __restrict__ g_hist,
                                                      const int* __restrict__ g_inter,
                                                      const float* __restrict__ smooth,
                                                      float* __restrict__ out) {
    const int b = blockIdx.x;
    const int lane = threadIdx.x;  // 0..63
    const float s = smooth[0];
    float acc = 0.0f;
    for (int c = lane; c < NC; c += 64) {
        float in = (float)g_inter[b * NC + c];
        float ht = (float)g_hist[b * NC + c];   // cnt_x + cnt_t
        // union = cnt_x + cnt_t - inter
        acc += (in + s) / (ht - in + s);
    }
#pragma unroll
    for (int off = 32; off > 0; off >>= 1)
        acc += __shfl_down(acc, off, 64);
    if (lane == 0) out[b] = acc / (float)NC;
}

extern "C" void kernel_launch(void* const* d_in, const int* in_sizes, int n_in,
                              void* d_out, int out_size, void* d_ws, size_t ws_size,
                              hipStream_t stream) {
    const int* x = (const int*)d_in[0];
    const int* t = (const int*)d_in[1];
    const float* smooth = (const float*)d_in[2];
    float* out = (float*)d_out;

    int* g_hist = (int*)d_ws;
    int* g_inter = g_hist + NB * NC;

    hipMemsetAsync(d_ws, 0, 2 * NB * NC * sizeof(int), stream);

    dim3 grid(HW / PIX_PER_BLOCK, NB);  // 64 x 32 = 2048 blocks
    hist_kernel<<<grid, THREADS, 0, stream>>>(x, t, g_hist, g_inter);
    finalize_kernel<<<NB, 64, 0, stream>>>(g_hist, g_inter, smooth, out);
}